// Round 1
// baseline (533.931 us; speedup 1.0000x reference)
//
#include <hip/hip_runtime.h>
#include <hip/hip_bf16.h>
#include <stdint.h>

typedef __bf16 bf16_t;
typedef bf16_t bf16x8 __attribute__((ext_vector_type(8)));
typedef float f32x4 __attribute__((ext_vector_type(4)));

#define GAS __attribute__((address_space(1)))
#define LAS __attribute__((address_space(3)))

// async global->LDS, 16 B per lane. LDS dest is wave-uniform base + lane*16.
__device__ __forceinline__ void async_load16(void* g, void* l) {
    __builtin_amdgcn_global_load_lds((GAS void*)g, (LAS void*)l, 16, 0, 0);
}

// ---------------- phase 1a: x fp32 -> bf16 (8 elems/thread) ----------------
__global__ void cast_f32_to_bf16(const float* __restrict__ x, bf16_t* __restrict__ y, long n8) {
    long t = (long)blockIdx.x * blockDim.x + threadIdx.x;
    if (t >= n8) return;
    const float4* xp = (const float4*)x;
    float4 v0 = xp[2 * t], v1 = xp[2 * t + 1];
    bf16x8 o;
    o[0] = (bf16_t)v0.x; o[1] = (bf16_t)v0.y; o[2] = (bf16_t)v0.z; o[3] = (bf16_t)v0.w;
    o[4] = (bf16_t)v1.x; o[5] = (bf16_t)v1.y; o[6] = (bf16_t)v1.z; o[7] = (bf16_t)v1.w;
    ((bf16x8*)y)[t] = o;
}

// ------------- phase 1b: dequant packed 4-bit codes -> bf16 W[N][K] -------------
// byte v at (o, p): W[o][2p] = cen[v>>4]*s, W[o][2p+1] = cen[v&15]*s, s = scl[o][p/32]
// hardcoded: K=4096 -> 2048 packed/row, 64 scale blocks/row (32 packed per block)
__global__ void dequant_w(const int* __restrict__ wp, const float* __restrict__ cen,
                          const float* __restrict__ scl, bf16_t* __restrict__ W, int n4) {
    __shared__ float c[16];
    if (threadIdx.x < 16) c[threadIdx.x] = cen[threadIdx.x];
    __syncthreads();
    int t = blockIdx.x * blockDim.x + threadIdx.x;
    if (t >= n4) return;
    int4 v = ((const int4*)wp)[t];
    int p   = t << 2;        // packed index (4 per thread, aligned -> one scale block)
    int o   = p >> 11;       // row
    int pin = p & 2047;
    float s = scl[(o << 6) + (pin >> 5)];
    int vv[4] = {v.x, v.y, v.z, v.w};
    bf16x8 outv;
#pragma unroll
    for (int i = 0; i < 4; ++i) {
        int b = vv[i];
        outv[2 * i]     = (bf16_t)(c[(b >> 4) & 15] * s);
        outv[2 * i + 1] = (bf16_t)(c[b & 15] * s);
    }
    ((bf16x8*)W)[t] = outv;
}

// ---------------- phase 2: bf16 NT GEMM  C[M,N] = A[M,K] * B[N,K]^T ----------------
// m97 structure: 128x128 tile, BK=32, 4 waves (2x2), each wave 64x64 via 4x4 of
// 16x16x32 MFMA. global_load_lds width-16 staging, single-buffered.
#define BM 128
#define BN 128
#define BK 32

__global__ __launch_bounds__(256, 3) void gemm_bf16_nt(
    const bf16_t* __restrict__ A, const bf16_t* __restrict__ B,
    float* __restrict__ C, int M, int N, int K)
{
    __shared__ bf16_t lA[BM * BK];   // 8 KB, row-major [128][32]
    __shared__ bf16_t lB[BN * BK];   // 8 KB

    const int tid  = threadIdx.x;
    const int wave = tid >> 6;
    const int lane = tid & 63;
    const int wm   = (wave >> 1) * 64;   // wave's sub-tile origin in tile
    const int wn   = (wave & 1) * 64;

    const long m0 = (long)blockIdx.y * BM;
    const long n0 = (long)blockIdx.x * BN;

    // staging: chunk c covers tile elements [8c, 8c+8): row = c>>2, k = (c&3)*8
    const int c0   = wave * 64 + lane;   // round 0 chunk
    const int c1   = c0 + 256;           // round 1 chunk
    const int row0 = c0 >> 2, kk0 = (c0 & 3) * 8;
    const int row1 = c1 >> 2, kk1 = (c1 & 3) * 8;

    bf16_t* An = (bf16_t*)A;
    bf16_t* Bn = (bf16_t*)B;
    bf16_t* a0 = An + (m0 + row0) * K + kk0;
    bf16_t* a1 = An + (m0 + row1) * K + kk1;
    bf16_t* b0 = Bn + (n0 + row0) * K + kk0;
    bf16_t* b1 = Bn + (n0 + row1) * K + kk1;

    // wave-uniform LDS bases (HW adds lane*16)
    bf16_t* lA0 = lA + (wave * 64) * 8;
    bf16_t* lA1 = lA0 + 256 * 8;
    bf16_t* lB0 = lB + (wave * 64) * 8;
    bf16_t* lB1 = lB0 + 256 * 8;

    // fragment read addresses: A[m=lane&15][k=(lane>>4)*8 + j], B symmetric
    const int qm = lane & 15;
    const int qk = (lane >> 4) * 8;
    const bf16_t* pa = lA + (wm + qm) * BK + qk;
    const bf16_t* pb = lB + (wn + qm) * BK + qk;

    f32x4 acc[4][4] = {};

    for (int k0 = 0; k0 < K; k0 += BK) {
        async_load16(a0 + k0, lA0);
        async_load16(a1 + k0, lA1);
        async_load16(b0 + k0, lB0);
        async_load16(b1 + k0, lB1);
        __syncthreads();   // drains vmcnt before barrier (compiler-emitted)
        bf16x8 af[4], bfv[4];
#pragma unroll
        for (int i = 0; i < 4; ++i) af[i] = *(const bf16x8*)(pa + i * 16 * BK);
#pragma unroll
        for (int j = 0; j < 4; ++j) bfv[j] = *(const bf16x8*)(pb + j * 16 * BK);
#pragma unroll
        for (int i = 0; i < 4; ++i)
#pragma unroll
            for (int j = 0; j < 4; ++j)
                acc[i][j] = __builtin_amdgcn_mfma_f32_16x16x32_bf16(af[i], bfv[j], acc[i][j], 0, 0, 0);
        __syncthreads();
    }

    // C/D layout: col = lane&15, row = (lane>>4)*4 + reg   [m89-verified]
    const int crow = (lane >> 4) * 4;
    const int ccol = lane & 15;
#pragma unroll
    for (int i = 0; i < 4; ++i)
#pragma unroll
        for (int r = 0; r < 4; ++r) {
            float* cp = C + (m0 + wm + i * 16 + crow + r) * N + (n0 + wn + ccol);
#pragma unroll
            for (int j = 0; j < 4; ++j)
                cp[j * 16] = acc[i][j][r];
        }
}

// ---------------- fallback (only if ws too small): fused, slow, correct ----------------
__global__ void fallback_qgemm(const float* __restrict__ x, const int* __restrict__ wp,
                               const float* __restrict__ cen, const float* __restrict__ scl,
                               float* __restrict__ out, int M, int N, int Kp) {
    __shared__ float c[16];
    if (threadIdx.x < 16) c[threadIdx.x] = cen[threadIdx.x];
    __syncthreads();
    int n = blockIdx.x * blockDim.x + threadIdx.x;
    int m = blockIdx.y;
    if (n >= N) return;
    const float* xr = x + (long)m * (Kp * 2);
    const int*   wr = wp + (long)n * Kp;
    int nb = Kp / 32;
    float acc = 0.f;
    for (int b = 0; b < nb; ++b) {
        float s  = scl[n * nb + b];
        float pa = 0.f;
        for (int j = 0; j < 32; ++j) {
            int v = wr[b * 32 + j];
            pa += xr[(b * 32 + j) * 2]     * c[(v >> 4) & 15]
                + xr[(b * 32 + j) * 2 + 1] * c[v & 15];
        }
        acc += s * pa;
    }
    out[(long)m * N + n] = acc;
}

extern "C" void kernel_launch(void* const* d_in, const int* in_sizes, int n_in,
                              void* d_out, int out_size, void* d_ws, size_t ws_size,
                              hipStream_t stream) {
    const float* x   = (const float*)d_in[0];
    const int*   wp  = (const int*)d_in[1];
    const float* cen = (const float*)d_in[2];
    const float* scl = (const float*)d_in[3];
    float* out = (float*)d_out;

    const int  IN  = 4096;
    const int  OUT = 4096;
    const long M   = (long)in_sizes[0] / IN;   // 8192

    size_t need = (size_t)(M * IN + (long)OUT * IN) * sizeof(bf16_t);  // 96 MB
    if (ws_size >= need) {
        bf16_t* xb = (bf16_t*)d_ws;
        bf16_t* Wb = xb + M * IN;
        long n8 = M * IN / 8;
        cast_f32_to_bf16<<<dim3((unsigned)((n8 + 255) / 256)), dim3(256), 0, stream>>>(x, xb, n8);
        int n4 = OUT * (IN / 2) / 4;
        dequant_w<<<dim3((n4 + 255) / 256), dim3(256), 0, stream>>>(wp, cen, scl, Wb, n4);
        dim3 grid(OUT / BN, (unsigned)(M / BM));
        gemm_bf16_nt<<<grid, dim3(256), 0, stream>>>(xb, Wb, out, (int)M, OUT, IN);
    } else {
        dim3 grid(OUT / 256, (unsigned)M);
        fallback_qgemm<<<grid, dim3(256), 0, stream>>>(x, wp, cen, scl, out, (int)M, OUT, IN / 2);
    }
}

// Round 2
// 529.108 us; speedup vs baseline: 1.0091x; 1.0091x over previous
//
#include <hip/hip_runtime.h>
#include <hip/hip_bf16.h>
#include <stdint.h>

typedef __bf16 bf16_t;
typedef bf16_t bf16x4 __attribute__((ext_vector_type(4)));
typedef bf16_t bf16x8 __attribute__((ext_vector_type(8)));
typedef float f32x4 __attribute__((ext_vector_type(4)));

#define GAS __attribute__((address_space(1)))
#define LAS __attribute__((address_space(3)))

__device__ __forceinline__ void async_load16(void* g, void* l) {
    __builtin_amdgcn_global_load_lds((GAS void*)g, (LAS void*)l, 16, 0, 0);
}

// ---------- phase 1 (merged): cast x->bf16  +  dequant W->bf16 ----------
// blocks [0, castBlocks): cast, 4 f32/thread (fully-coalesced float4 read)
// blocks [castBlocks, ...): dequant, 4 packed int32/thread -> 8 bf16
__global__ void prep_kernel(const float* __restrict__ x, bf16_t* __restrict__ xb,
                            const int* __restrict__ wp, const float* __restrict__ cen,
                            const float* __restrict__ scl, bf16_t* __restrict__ W,
                            int castBlocks) {
    if ((int)blockIdx.x < castBlocks) {
        long t = (long)blockIdx.x * blockDim.x + threadIdx.x;
        float4 v = ((const float4*)x)[t];
        bf16x4 o;
        o[0] = (bf16_t)v.x; o[1] = (bf16_t)v.y; o[2] = (bf16_t)v.z; o[3] = (bf16_t)v.w;
        ((bf16x4*)xb)[t] = o;
    } else {
        __shared__ float c[16];
        if (threadIdx.x < 16) c[threadIdx.x] = cen[threadIdx.x];
        __syncthreads();
        int t = ((int)blockIdx.x - castBlocks) * blockDim.x + threadIdx.x;
        int4 v = ((const int4*)wp)[t];
        int p   = t << 2;        // packed index (4/thread, aligned -> one scale block)
        int o   = p >> 11;       // row (2048 packed per row)
        int pin = p & 2047;
        float s = scl[(o << 6) + (pin >> 5)];   // 64 scale blocks/row, 32 packed each
        int vv[4] = {v.x, v.y, v.z, v.w};
        bf16x8 outv;
#pragma unroll
        for (int i = 0; i < 4; ++i) {
            int b = vv[i];
            outv[2 * i]     = (bf16_t)(c[(b >> 4) & 15] * s);
            outv[2 * i + 1] = (bf16_t)(c[b & 15] * s);
        }
        ((bf16x8*)W)[t] = outv;
    }
}

// ---------------- phase 2: bf16 NT GEMM  C[M,N] = A[M,K] * B[N,K]^T ----------------
// m97 structure: 128x128 tile, BK=32, 4 waves (2x2), each wave 64x64 via 4x4 of
// 16x16x32 MFMA. global_load_lds width-16 staging.
// LDS layout XOR-swizzled at 16B-chunk granularity to kill ds_read_b128 bank
// conflicts: chunk (row, kc) -> slot row*4 + (kc ^ ((row>>1)&3)).
// Staging permutes the *global* kc per lane (LDS dest is fixed = lane*16).
#define BM 128
#define BN 128
#define BK 32

__global__ __launch_bounds__(256, 3) void gemm_bf16_nt(
    const bf16_t* __restrict__ A, const bf16_t* __restrict__ B,
    float* __restrict__ C, int M, int N, int K)
{
    __shared__ bf16_t lA[BM * BK];   // 8 KB
    __shared__ bf16_t lB[BN * BK];   // 8 KB

    const int tid  = threadIdx.x;
    const int wave = tid >> 6;
    const int lane = tid & 63;
    const int wm   = (wave >> 1) * 64;
    const int wn   = (wave & 1) * 64;

    const long m0 = (long)blockIdx.y * BM;
    const long n0 = (long)blockIdx.x * BN;

    // staging: LDS slot s = round*256 + wave*64 + lane holds global chunk
    // (row = s>>2, kc = (s&3) ^ ((s>>3)&3))  [inverse of the XOR swizzle]
    const int s0   = wave * 64 + lane;
    const int s1   = s0 + 256;
    const int row0 = s0 >> 2, kk0 = ((s0 & 3) ^ ((s0 >> 3) & 3)) * 8;
    const int row1 = s1 >> 2, kk1 = ((s1 & 3) ^ ((s1 >> 3) & 3)) * 8;

    bf16_t* An = (bf16_t*)A;
    bf16_t* Bn = (bf16_t*)B;
    bf16_t* a0 = An + (m0 + row0) * K + kk0;
    bf16_t* a1 = An + (m0 + row1) * K + kk1;
    bf16_t* b0 = Bn + (n0 + row0) * K + kk0;
    bf16_t* b1 = Bn + (n0 + row1) * K + kk1;

    // wave-uniform LDS bases (HW adds lane*16)
    bf16_t* lA0 = lA + (wave * 64) * 8;
    bf16_t* lA1 = lA0 + 256 * 8;
    bf16_t* lB0 = lB + (wave * 64) * 8;
    bf16_t* lB1 = lB0 + 256 * 8;

    // fragment reads: A[m=lane&15][k=(lane>>4)*8+j]; swizzled k-chunk
    const int qm = lane & 15;
    const int kc = lane >> 4;
    const int sw = (qm >> 1) & 3;          // (row>>1)&3 with row = 16*i + qm
    const int kks = (kc ^ sw) * 8;
    const bf16_t* pa = lA + (wm + qm) * BK + kks;
    const bf16_t* pb = lB + (wn + qm) * BK + kks;

    f32x4 acc[4][4] = {};

    for (int k0 = 0; k0 < K; k0 += BK) {
        async_load16(a0 + k0, lA0);
        async_load16(a1 + k0, lA1);
        async_load16(b0 + k0, lB0);
        async_load16(b1 + k0, lB1);
        __syncthreads();
        bf16x8 af[4], bfv[4];
#pragma unroll
        for (int i = 0; i < 4; ++i) af[i] = *(const bf16x8*)(pa + i * 16 * BK);
#pragma unroll
        for (int j = 0; j < 4; ++j) bfv[j] = *(const bf16x8*)(pb + j * 16 * BK);
#pragma unroll
        for (int i = 0; i < 4; ++i)
#pragma unroll
            for (int j = 0; j < 4; ++j)
                acc[i][j] = __builtin_amdgcn_mfma_f32_16x16x32_bf16(af[i], bfv[j], acc[i][j], 0, 0, 0);
        __syncthreads();
    }

    // C/D layout: col = lane&15, row = (lane>>4)*4 + reg   [m89-verified]
    const int crow = (lane >> 4) * 4;
    const int ccol = lane & 15;
#pragma unroll
    for (int i = 0; i < 4; ++i)
#pragma unroll
        for (int r = 0; r < 4; ++r) {
            float* cp = C + (m0 + wm + i * 16 + crow + r) * N + (n0 + wn + ccol);
#pragma unroll
            for (int j = 0; j < 4; ++j)
                cp[j * 16] = acc[i][j][r];
        }
}

// ---------------- fallback (only if ws too small): fused, slow, correct ----------------
__global__ void fallback_qgemm(const float* __restrict__ x, const int* __restrict__ wp,
                               const float* __restrict__ cen, const float* __restrict__ scl,
                               float* __restrict__ out, int M, int N, int Kp) {
    __shared__ float c[16];
    if (threadIdx.x < 16) c[threadIdx.x] = cen[threadIdx.x];
    __syncthreads();
    int n = blockIdx.x * blockDim.x + threadIdx.x;
    int m = blockIdx.y;
    if (n >= N) return;
    const float* xr = x + (long)m * (Kp * 2);
    const int*   wr = wp + (long)n * Kp;
    int nb = Kp / 32;
    float acc = 0.f;
    for (int b = 0; b < nb; ++b) {
        float s  = scl[n * nb + b];
        float pa = 0.f;
        for (int j = 0; j < 32; ++j) {
            int v = wr[b * 32 + j];
            pa += xr[(b * 32 + j) * 2]     * c[(v >> 4) & 15]
                + xr[(b * 32 + j) * 2 + 1] * c[v & 15];
        }
        acc += s * pa;
    }
    out[(long)m * N + n] = acc;
}

extern "C" void kernel_launch(void* const* d_in, const int* in_sizes, int n_in,
                              void* d_out, int out_size, void* d_ws, size_t ws_size,
                              hipStream_t stream) {
    const float* x   = (const float*)d_in[0];
    const int*   wp  = (const int*)d_in[1];
    const float* cen = (const float*)d_in[2];
    const float* scl = (const float*)d_in[3];
    float* out = (float*)d_out;

    const int  IN  = 4096;
    const int  OUT = 4096;
    const long M   = (long)in_sizes[0] / IN;   // 8192

    size_t need = (size_t)(M * IN + (long)OUT * IN) * sizeof(bf16_t);  // 96 MB
    if (ws_size >= need) {
        bf16_t* xb = (bf16_t*)d_ws;
        bf16_t* Wb = xb + M * IN;
        int castBlocks = (int)(M * IN / 4 / 256);        // 4 f32 per thread
        int deqBlocks  = OUT * (IN / 2) / 4 / 256;       // 4 int32 per thread
        prep_kernel<<<dim3(castBlocks + deqBlocks), dim3(256), 0, stream>>>(
            x, xb, wp, cen, scl, Wb, castBlocks);
        dim3 grid(OUT / BN, (unsigned)(M / BM));
        gemm_bf16_nt<<<grid, dim3(256), 0, stream>>>(xb, Wb, out, (int)M, OUT, IN);
    } else {
        dim3 grid(OUT / 256, (unsigned)M);
        fallback_qgemm<<<grid, dim3(256), 0, stream>>>(x, wp, cen, scl, out, (int)M, OUT, IN / 2);
    }
}

// Round 3
// 475.556 us; speedup vs baseline: 1.1227x; 1.1126x over previous
//
#include <hip/hip_runtime.h>
#include <hip/hip_bf16.h>
#include <stdint.h>

typedef __bf16 bf16_t;
typedef bf16_t bf16x4 __attribute__((ext_vector_type(4)));
typedef bf16_t bf16x8 __attribute__((ext_vector_type(8)));
typedef float f32x4 __attribute__((ext_vector_type(4)));

#define GAS __attribute__((address_space(1)))
#define LAS __attribute__((address_space(3)))

__device__ __forceinline__ void async_load16(const void* g, void* l) {
    __builtin_amdgcn_global_load_lds((const GAS void*)g, (LAS void*)l, 16, 0, 0);
}

// ---------- phase 1 (merged): cast x->bf16  +  dequant W->bf16 ----------
__global__ void prep_kernel(const float* __restrict__ x, bf16_t* __restrict__ xb,
                            const int* __restrict__ wp, const float* __restrict__ cen,
                            const float* __restrict__ scl, bf16_t* __restrict__ W,
                            int castBlocks) {
    if ((int)blockIdx.x < castBlocks) {
        long t = (long)blockIdx.x * blockDim.x + threadIdx.x;
        float4 v = ((const float4*)x)[t];
        bf16x4 o;
        o[0] = (bf16_t)v.x; o[1] = (bf16_t)v.y; o[2] = (bf16_t)v.z; o[3] = (bf16_t)v.w;
        ((bf16x4*)xb)[t] = o;
    } else {
        __shared__ float c[16];
        if (threadIdx.x < 16) c[threadIdx.x] = cen[threadIdx.x];
        __syncthreads();
        int t = ((int)blockIdx.x - castBlocks) * blockDim.x + threadIdx.x;
        int4 v = ((const int4*)wp)[t];
        int p   = t << 2;        // packed index (4/thread, aligned -> one scale block)
        int o   = p >> 11;       // row (2048 packed per row)
        int pin = p & 2047;
        float s = scl[(o << 6) + (pin >> 5)];   // 64 scale blocks/row, 32 packed each
        int vv[4] = {v.x, v.y, v.z, v.w};
        bf16x8 outv;
#pragma unroll
        for (int i = 0; i < 4; ++i) {
            int b = vv[i];
            outv[2 * i]     = (bf16_t)(c[(b >> 4) & 15] * s);
            outv[2 * i + 1] = (bf16_t)(c[b & 15] * s);
        }
        ((bf16x8*)W)[t] = outv;
    }
}

// ---------------- phase 2: bf16 NT GEMM, BK=64 ----------------
// 128x128 tile, BK=64 (32 KB LDS, 2 barriers per 64-K step -> 32 MFMA/wave per
// barrier-pair). XOR swizzle at 16B-chunk granularity: (row,kc) -> slot
// row*8 + (kc ^ (row&7)); staging permutes global kc (LDS dest fixed lane*16).
#define BM 128
#define BN 128
#define BK 64

__global__ __launch_bounds__(256, 4) void gemm_bf16_nt(
    const bf16_t* __restrict__ A, const bf16_t* __restrict__ B,
    float* __restrict__ C, int M, int N, int K)
{
    __shared__ bf16_t lA[BM * BK];   // 16 KB
    __shared__ bf16_t lB[BN * BK];   // 16 KB

    const int tid  = threadIdx.x;
    const int wave = tid >> 6;
    const int lane = tid & 63;
    const int wm   = (wave >> 1) * 64;
    const int wn   = (wave & 1) * 64;

    const long m0 = (long)blockIdx.y * BM;
    const long n0 = (long)blockIdx.x * BN;

    // staging: 1024 chunks per matrix, 4 rounds of 256 threads.
    // slot s = r*256 + tid : row = s>>3, kc_slot = s&7, global kc = kc_slot^(row&7)
    const bf16_t* aP[4];
    const bf16_t* bP[4];
    int ldsOff[4];
#pragma unroll
    for (int r = 0; r < 4; ++r) {
        int s   = r * 256 + tid;
        int row = s >> 3;
        int kg  = (s & 7) ^ (row & 7);
        aP[r] = A + (m0 + row) * K + kg * 8;
        bP[r] = B + (n0 + row) * K + kg * 8;
        ldsOff[r] = (r * 256 + wave * 64) * 8;   // wave-uniform elem offset
    }

    // fragment reads: A[m=lane&15][k=(lane>>4)*8+j] per 32-K half
    const int qm = lane & 15;
    const int kcb = lane >> 4;          // 0..3
    const int swk = qm & 7;             // swizzle key (row&7 == qm&7 here)
    const bf16_t* pa = lA + (wm + qm) * BK;
    const bf16_t* pb = lB + (wn + qm) * BK;
    const int co0 = (kcb ^ swk) * 8;          // half t=0 chunk offset (elems)
    const int co1 = ((kcb + 4) ^ swk) * 8;    // half t=1

    f32x4 acc[4][4] = {};

    for (int k0 = 0; k0 < K; k0 += BK) {
#pragma unroll
        for (int r = 0; r < 4; ++r) async_load16(aP[r] + k0, lA + ldsOff[r]);
#pragma unroll
        for (int r = 0; r < 4; ++r) async_load16(bP[r] + k0, lB + ldsOff[r]);
        __syncthreads();

        bf16x8 af[4], bfv[4];
        // half 0
#pragma unroll
        for (int i = 0; i < 4; ++i) af[i] = *(const bf16x8*)(pa + i * 16 * BK + co0);
#pragma unroll
        for (int j = 0; j < 4; ++j) bfv[j] = *(const bf16x8*)(pb + j * 16 * BK + co0);
#pragma unroll
        for (int i = 0; i < 4; ++i)
#pragma unroll
            for (int j = 0; j < 4; ++j)
                acc[i][j] = __builtin_amdgcn_mfma_f32_16x16x32_bf16(af[i], bfv[j], acc[i][j], 0, 0, 0);
        // half 1
#pragma unroll
        for (int i = 0; i < 4; ++i) af[i] = *(const bf16x8*)(pa + i * 16 * BK + co1);
#pragma unroll
        for (int j = 0; j < 4; ++j) bfv[j] = *(const bf16x8*)(pb + j * 16 * BK + co1);
#pragma unroll
        for (int i = 0; i < 4; ++i)
#pragma unroll
            for (int j = 0; j < 4; ++j)
                acc[i][j] = __builtin_amdgcn_mfma_f32_16x16x32_bf16(af[i], bfv[j], acc[i][j], 0, 0, 0);
        __syncthreads();
    }

    // C/D layout: col = lane&15, row = (lane>>4)*4 + reg   [m89-verified]
    const int crow = (lane >> 4) * 4;
    const int ccol = lane & 15;
#pragma unroll
    for (int i = 0; i < 4; ++i)
#pragma unroll
        for (int r = 0; r < 4; ++r) {
            float* cp = C + (m0 + wm + i * 16 + crow + r) * N + (n0 + wn + ccol);
#pragma unroll
            for (int j = 0; j < 4; ++j)
                cp[j * 16] = acc[i][j][r];
        }
}

// ---------------- fallback (only if ws too small): fused, slow, correct ----------------
__global__ void fallback_qgemm(const float* __restrict__ x, const int* __restrict__ wp,
                               const float* __restrict__ cen, const float* __restrict__ scl,
                               float* __restrict__ out, int M, int N, int Kp) {
    __shared__ float c[16];
    if (threadIdx.x < 16) c[threadIdx.x] = cen[threadIdx.x];
    __syncthreads();
    int n = blockIdx.x * blockDim.x + threadIdx.x;
    int m = blockIdx.y;
    if (n >= N) return;
    const float* xr = x + (long)m * (Kp * 2);
    const int*   wr = wp + (long)n * Kp;
    int nb = Kp / 32;
    float acc = 0.f;
    for (int b = 0; b < nb; ++b) {
        float s  = scl[n * nb + b];
        float pa = 0.f;
        for (int j = 0; j < 32; ++j) {
            int v = wr[b * 32 + j];
            pa += xr[(b * 32 + j) * 2]     * c[(v >> 4) & 15]
                + xr[(b * 32 + j) * 2 + 1] * c[v & 15];
        }
        acc += s * pa;
    }
    out[(long)m * N + n] = acc;
}

extern "C" void kernel_launch(void* const* d_in, const int* in_sizes, int n_in,
                              void* d_out, int out_size, void* d_ws, size_t ws_size,
                              hipStream_t stream) {
    const float* x   = (const float*)d_in[0];
    const int*   wp  = (const int*)d_in[1];
    const float* cen = (const float*)d_in[2];
    const float* scl = (const float*)d_in[3];
    float* out = (float*)d_out;

    const int  IN  = 4096;
    const int  OUT = 4096;
    const long M   = (long)in_sizes[0] / IN;   // 8192

    size_t need = (size_t)(M * IN + (long)OUT * IN) * sizeof(bf16_t);  // 96 MB
    if (ws_size >= need) {
        bf16_t* xb = (bf16_t*)d_ws;
        bf16_t* Wb = xb + M * IN;
        int castBlocks = (int)(M * IN / 4 / 256);        // 4 f32 per thread
        int deqBlocks  = OUT * (IN / 2) / 4 / 256;       // 4 int32 per thread
        prep_kernel<<<dim3(castBlocks + deqBlocks), dim3(256), 0, stream>>>(
            x, xb, wp, cen, scl, Wb, castBlocks);
        dim3 grid(OUT / BN, (unsigned)(M / BM));
        gemm_bf16_nt<<<grid, dim3(256), 0, stream>>>(xb, Wb, out, (int)M, OUT, IN);
    } else {
        dim3 grid(OUT / 256, (unsigned)M);
        fallback_qgemm<<<grid, dim3(256), 0, stream>>>(x, wp, cen, scl, out, (int)M, OUT, IN / 2);
    }
}